// Round 6
// baseline (409.114 us; speedup 1.0000x reference)
//
#include <hip/hip_runtime.h>
#include <hip/hip_bf16.h>
#include <math.h>

typedef __bf16 bf16;
typedef __bf16 bf16x4 __attribute__((ext_vector_type(4)));
typedef __bf16 bf16x8 __attribute__((ext_vector_type(8)));
typedef float f32x4 __attribute__((ext_vector_type(4)));

#define DIM 768
#define HID 3072
#define HID2 1536
#define NLEV 9
#define SEQ 2048
#define ROWS 4096            // BATCH*SEQ
#define MAXPAD 5248          // ROWS + NLEV*128 (rounded)
#define MAXTILES 41          // MAXPAD/128

// fast tanh-GELU: max |err| vs exact-erf gelu ~5e-4
__device__ __forceinline__ float fast_gelu(float v) {
    float v2 = v * v;
    float twou = v * (1.59576912f + 0.071354816f * v2);
    float t = __expf(twou);
    return v * t / (t + 1.0f);
}

// ================= PREP bodies =================

__device__ __forceinline__ void ln_body(int row, float* sm,
                                        const float* __restrict__ x,
                                        const float* __restrict__ gamma,
                                        const float* __restrict__ beta,
                                        bf16* __restrict__ xn) {
    int tid = threadIdx.x;
    const float* xr = x + (size_t)row * DIM;
    float v0 = xr[tid], v1 = xr[tid + 256], v2 = xr[tid + 512];
    float s = v0 + v1 + v2;
    float q = v0 * v0 + v1 * v1 + v2 * v2;
    for (int off = 32; off; off >>= 1) {
        s += __shfl_down(s, off, 64);
        q += __shfl_down(q, off, 64);
    }
    int wv = tid >> 6, ln = tid & 63;
    if (ln == 0) { sm[wv] = s; sm[4 + wv] = q; }
    __syncthreads();
    if (tid == 0) {
        float S = sm[0] + sm[1] + sm[2] + sm[3];
        float Q = sm[4] + sm[5] + sm[6] + sm[7];
        float m = S * (1.0f / DIM);
        float var = Q * (1.0f / DIM) - m * m;
        sm[8] = m;
        sm[9] = rsqrtf(var + 1e-5f);
    }
    __syncthreads();
    float m = sm[8], r = sm[9];
    bf16* xo = xn + (size_t)row * DIM;
    xo[tid]       = (bf16)((v0 - m) * r * gamma[tid]       + beta[tid]);
    xo[tid + 256] = (bf16)((v1 - m) * r * gamma[tid + 256] + beta[tid + 256]);
    xo[tid + 512] = (bf16)((v2 - m) * r * gamma[tid + 512] + beta[tid + 512]);
}

// 64x64 tile transpose: fp32 [R][C] -> bf16 [C][R]. sm = 64*65 floats.
__device__ __forceinline__ void transpose_body64(float* sm,
                                                 const float* __restrict__ inb,
                                                 bf16* __restrict__ outb,
                                                 int R, int C, int bx, int by) {
    int tid = threadIdx.x;
    int ty = tid >> 4;
    int tx4 = (tid & 15) * 4;
#pragma unroll
    for (int p = 0; p < 4; p++) {
        int rloc = p * 16 + ty;
        int row = by * 64 + rloc;
        float4 v = *(const float4*)(inb + (size_t)row * C + bx * 64 + tx4);
        sm[rloc * 65 + tx4 + 0] = v.x;
        sm[rloc * 65 + tx4 + 1] = v.y;
        sm[rloc * 65 + tx4 + 2] = v.z;
        sm[rloc * 65 + tx4 + 3] = v.w;
    }
    __syncthreads();
    int ch = tid & 7;
    int ocb = tid >> 3;
#pragma unroll
    for (int p = 0; p < 2; p++) {
        int oc = p * 32 + ocb;
        bf16x8 tmp;
#pragma unroll
        for (int k = 0; k < 8; k++) tmp[k] = (bf16)sm[(ch * 8 + k) * 65 + oc];
        *(bf16x8*)(outb + (size_t)(bx * 64 + oc) * R + by * 64 + ch * 8) = tmp;
    }
}

__device__ __forceinline__ void routing_body(float* sm,
                                             const int* __restrict__ levels_info,
                                             const float* __restrict__ lmw,
                                             float* __restrict__ mix,
                                             int* __restrict__ row_index,
                                             int* __restrict__ tile_meta,
                                             float* __restrict__ zbuf) {
    int* cnt = (int*)sm;
    int* cur = cnt + NLEV;
    int* off = cur + NLEV;
    float* mixv = (float*)(off + NLEV);
    int tid = threadIdx.x;
    if (tid < NLEV) { cnt[tid] = 0; cur[tid] = 0; }
    __syncthreads();
    for (int s = tid; s < SEQ; s += 256) {
        int d = levels_info[s * 4];
        d = d < 0 ? 0 : (d > 8 ? 8 : d);
        atomicAdd(&cnt[d], 1);
    }
    for (int i = tid; i < MAXPAD; i += 256) row_index[i] = -1;
    for (int i = tid; i < 512; i += 256) zbuf[i] = 0.0f;   // 2 KB zero page
    __syncthreads();
    if (tid == 0) {
        float mx = lmw[0];
        for (int l = 1; l < NLEV; l++) mx = fmaxf(mx, lmw[l]);
        float denom = 0.f;
        for (int l = 0; l < NLEV; l++) denom += (float)cnt[l] * expf(lmw[l] - mx);
        float inv = 1.0f / denom;
        int running = 0, t = 0;
        for (int l = 0; l < NLEV; l++) {
            mixv[l] = expf(lmw[l] - mx) * inv;
            off[l] = running;
            int seg = (2 * cnt[l] + 127) & ~127;
            for (int k = 0; k < seg / 128; k++) tile_meta[t++] = l;
            running += seg;
        }
        for (; t < MAXTILES; t++) tile_meta[t] = -1;
    }
    __syncthreads();
    for (int s = tid; s < SEQ; s += 256) {
        int d = levels_info[s * 4];
        d = d < 0 ? 0 : (d > 8 ? 8 : d);
        int p = atomicAdd(&cur[d], 2);
        row_index[off[d] + p]     = s;
        row_index[off[d] + p + 1] = s + SEQ;
        mix[s] = mixv[d];
    }
}

// ---------------- fat prep kernel ----------------
__global__ __launch_bounds__(256) void prep_kernel(const float* __restrict__ x,
                                                   const int* __restrict__ levels_info,
                                                   const float* __restrict__ gamma,
                                                   const float* __restrict__ beta,
                                                   const float* __restrict__ W1,
                                                   const float* __restrict__ W2,
                                                   const float* __restrict__ A1,
                                                   const float* __restrict__ A2,
                                                   const float* __restrict__ lmw,
                                                   bf16* __restrict__ Xn,
                                                   bf16* __restrict__ W1t,
                                                   bf16* __restrict__ W2t,
                                                   bf16* __restrict__ A1t,
                                                   bf16* __restrict__ A2t,
                                                   float* __restrict__ mix,
                                                   int* __restrict__ row_index,
                                                   int* __restrict__ tile_meta,
                                                   float* __restrict__ zbuf) {
    __shared__ __align__(16) float sm[64 * 65];
    int bid = blockIdx.x;
    if (bid == 0) { routing_body(sm, levels_info, lmw, mix, row_index, tile_meta, zbuf); return; }
    bid -= 1;
    if (bid < ROWS) { ln_body(bid, sm, x, gamma, beta, Xn); return; }
    bid -= ROWS;
    if (bid < 576) {
        transpose_body64(sm, W1, W1t, DIM, HID, bid % 48, bid / 48);
        return;
    }
    bid -= 576;
    if (bid < 576) {
        transpose_body64(sm, W2, W2t, HID, DIM, bid % 12, bid / 12);
        return;
    }
    bid -= 576;
    if (bid < 2592) {
        int bz = bid / 288, r = bid % 288;
        transpose_body64(sm, A1 + (size_t)bz * DIM * HID2, A1t + (size_t)bz * DIM * HID2,
                         DIM, HID2, r % 24, r / 24);
        return;
    }
    bid -= 2592;
    {
        int bz = bid / 288, r = bid % 288;
        transpose_body64(sm, A2 + (size_t)bz * HID2 * DIM, A2t + (size_t)bz * HID2 * DIM,
                         HID2, DIM, r % 12, r / 12);
    }
}

// ---------------- barrier-free register GEMM K-loop (K=768, 24 iters) ----------------
// Per wave: 64x64 C tile. Fragments loaded straight global->VGPR, 2-stage pipeline.
// pa[i]/pb[i] are per-lane row pointers (already include the lane's k-chunk offset).
__device__ __forceinline__ void gemm_k768(const bf16* pa0, const bf16* pa1,
                                          const bf16* pa2, const bf16* pa3,
                                          const bf16* pb0, const bf16* pb1,
                                          const bf16* pb2, const bf16* pb3,
                                          f32x4 (&acc)[4][4]) {
    const bf16* pa[4] = {pa0, pa1, pa2, pa3};
    const bf16* pb[4] = {pb0, pb1, pb2, pb3};
    bf16x8 af[2][4], bfr[2][4];
#pragma unroll
    for (int i = 0; i < 4; i++) {
        af[0][i]  = *(const bf16x8*)(pa[i]);
        bfr[0][i] = *(const bf16x8*)(pb[i]);
        af[1][i]  = *(const bf16x8*)(pa[i] + 32);
        bfr[1][i] = *(const bf16x8*)(pb[i] + 32);
    }
#pragma unroll
    for (int kt = 0; kt < 24; kt++) {
        int s = kt & 1;
#pragma unroll
        for (int i = 0; i < 4; i++)
#pragma unroll
            for (int j = 0; j < 4; j++)
                acc[i][j] = __builtin_amdgcn_mfma_f32_16x16x32_bf16(af[s][i], bfr[s][j], acc[i][j], 0, 0, 0);
        if (kt + 2 < 24) {
#pragma unroll
            for (int i = 0; i < 4; i++) {
                af[s][i]  = *(const bf16x8*)(pa[i] + (kt + 2) * 32);
                bfr[s][i] = *(const bf16x8*)(pb[i] + (kt + 2) * 32);
            }
        }
    }
}

#define ACC_INIT(acc) \
    _Pragma("unroll") for (int i = 0; i < 4; i++) \
    _Pragma("unroll") for (int j = 0; j < 4; j++) acc[i][j] = (f32x4){0.f, 0.f, 0.f, 0.f};

// ---------------- mlp1: gemm1 + agemm1, no LDS, no barriers ----------------
__global__ __launch_bounds__(256) void mlp1_kernel(const bf16* __restrict__ Xn,
                                                   const bf16* __restrict__ W1t,
                                                   const float* __restrict__ b1,
                                                   bf16* __restrict__ H,
                                                   const bf16* __restrict__ A1t,
                                                   const float* __restrict__ a1b,
                                                   const int* __restrict__ row_index,
                                                   const int* __restrict__ tile_meta,
                                                   const bf16* __restrict__ zbuf,
                                                   bf16* __restrict__ HL) {
    int bid = blockIdx.x, tid = threadIdx.x;
    int lane = tid & 63, wv = tid >> 6, wm = wv >> 1, wn = wv & 1;
    int lr = lane & 15, lc = (lane >> 4) * 8;
    f32x4 acc[4][4];
    ACC_INIT(acc);

    if (bid < 768) {
        // XCD-locality: nb locked to bid&7 (3 W1t strips/XCD), mb slow
        int nb = (bid & 7) * 3 + ((bid >> 3) % 3);
        int mb = bid / 24;
        const bf16* pa[4];
        const bf16* pb[4];
#pragma unroll
        for (int i = 0; i < 4; i++) {
            pa[i] = Xn  + (size_t)(mb * 128 + wm * 64 + i * 16 + lr) * DIM + lc;
            pb[i] = W1t + (size_t)(nb * 128 + wn * 64 + i * 16 + lr) * DIM + lc;
        }
        gemm_k768(pa[0], pa[1], pa[2], pa[3], pb[0], pb[1], pb[2], pb[3], acc);
        int rbase = mb * 128 + wm * 64 + ((lane >> 4) << 2);
        int cbase = nb * 128 + wn * 64 + lr;
#pragma unroll
        for (int j = 0; j < 4; j++) {
            int c = cbase + j * 16;
            float bias = b1[c];
#pragma unroll
            for (int i = 0; i < 4; i++)
#pragma unroll
                for (int r = 0; r < 4; r++) {
                    int row = rbase + i * 16 + r;
                    H[(size_t)row * HID + c] = (bf16)fast_gelu(acc[i][j][r] + bias);
                }
        }
    } else {
        int t2 = bid - 768;
        int nb = t2 % 12, t = t2 / 12;
        int lvl = tile_meta[t];
        if (lvl < 0) return;
        const bf16* pa[4];
        const bf16* pb[4];
        const bf16* Bl = A1t + (size_t)lvl * HID2 * DIM;
#pragma unroll
        for (int i = 0; i < 4; i++) {
            int ridx = row_index[t * 128 + wm * 64 + i * 16 + lr];
            pa[i] = (ridx >= 0) ? (Xn + (size_t)ridx * DIM + lc) : (zbuf + lc);
            pb[i] = Bl + (size_t)(nb * 128 + wn * 64 + i * 16 + lr) * DIM + lc;
        }
        gemm_k768(pa[0], pa[1], pa[2], pa[3], pb[0], pb[1], pb[2], pb[3], acc);
        int rbase = wm * 64 + ((lane >> 4) << 2);
        int cbase = nb * 128 + wn * 64 + lr;
#pragma unroll
        for (int j = 0; j < 4; j++) {
            int c = cbase + j * 16;
            float bias = a1b[lvl * HID2 + c];
#pragma unroll
            for (int i = 0; i < 4; i++)
#pragma unroll
                for (int r = 0; r < 4; r++) {
                    int rl = rbase + i * 16 + r;
                    HL[(size_t)(t * 128 + rl) * HID2 + c] = (bf16)fmaxf(acc[i][j][r] + bias, 0.0f);
                }
        }
    }
}

// ---------------- mlp2: gemm2 splitK4 + agemm2 splitK2, no LDS, no barriers ----------------
__global__ __launch_bounds__(256) void mlp2_kernel(const bf16* __restrict__ H,
                                                   const bf16* __restrict__ W2t,
                                                   bf16* __restrict__ part,   // [4][ROWS*DIM]
                                                   const bf16* __restrict__ HL,
                                                   const bf16* __restrict__ A2t,
                                                   const float* __restrict__ a2b,
                                                   const int* __restrict__ row_index,
                                                   const int* __restrict__ tile_meta,
                                                   bf16* __restrict__ apart) { // [2][ROWS*DIM]
    int bid = blockIdx.x, tid = threadIdx.x;
    int lane = tid & 63, wv = tid >> 6, wm = wv >> 1, wn = wv & 1;
    int lr = lane & 15, lc = (lane >> 4) * 8;
    f32x4 acc[4][4];
    ACC_INIT(acc);

    if (bid < 768) {
        // XCD-locality: (nb,ks) combo locked to bid&7, mb slow
        int c24 = (bid & 7) * 3 + ((bid >> 3) % 3);
        int nb = c24 >> 2, ks = c24 & 3;
        int mb = bid / 24;
        const bf16* pa[4];
        const bf16* pb[4];
#pragma unroll
        for (int i = 0; i < 4; i++) {
            pa[i] = H   + (size_t)(mb * 128 + wm * 64 + i * 16 + lr) * HID + ks * 768 + lc;
            pb[i] = W2t + (size_t)(nb * 128 + wn * 64 + i * 16 + lr) * HID + ks * 768 + lc;
        }
        gemm_k768(pa[0], pa[1], pa[2], pa[3], pb[0], pb[1], pb[2], pb[3], acc);
        bf16* pk = part + (size_t)ks * ROWS * DIM;
        int rbase = mb * 128 + wm * 64 + ((lane >> 4) << 2);
        int cbase = nb * 128 + wn * 64 + lr;
#pragma unroll
        for (int j = 0; j < 4; j++) {
            int c = cbase + j * 16;
#pragma unroll
            for (int i = 0; i < 4; i++)
#pragma unroll
                for (int r = 0; r < 4; r++) {
                    int row = rbase + i * 16 + r;
                    pk[(size_t)row * DIM + c] = (bf16)acc[i][j][r];
                }
        }
    } else {
        int t2 = bid - 768;
        int cc = t2 % 12;
        int nb = cc >> 1, ks = cc & 1;
        int t = t2 / 12;
        int lvl = tile_meta[t];
        if (lvl < 0) return;
        const bf16* pa[4];
        const bf16* pb[4];
        const bf16* Bl = A2t + (size_t)lvl * DIM * HID2;
#pragma unroll
        for (int i = 0; i < 4; i++) {
            pa[i] = HL + (size_t)(t * 128 + wm * 64 + i * 16 + lr) * HID2 + ks * 768 + lc;
            pb[i] = Bl + (size_t)(nb * 128 + wn * 64 + i * 16 + lr) * HID2 + ks * 768 + lc;
        }
        gemm_k768(pa[0], pa[1], pa[2], pa[3], pb[0], pb[1], pb[2], pb[3], acc);
        bf16* apk = apart + (size_t)ks * ROWS * DIM;
        int rbase = wm * 64 + ((lane >> 4) << 2);
        int cbase = nb * 128 + wn * 64 + lr;
#pragma unroll
        for (int i = 0; i < 4; i++)
#pragma unroll
            for (int r = 0; r < 4; r++) {
                int rl = rbase + i * 16 + r;
                int rg = row_index[t * 128 + rl];
                if (rg >= 0) {
#pragma unroll
                    for (int j = 0; j < 4; j++) {
                        int c = cbase + j * 16;
                        float v = acc[i][j][r] + (ks == 0 ? a2b[lvl * DIM + c] : 0.0f);
                        apk[(size_t)rg * DIM + c] = (bf16)v;
                    }
                }
            }
    }
}

// ---------------- combine: out = (1-mix)*(Σ4 part + b2) + mix*(Σ2 apart) ----------------
__global__ __launch_bounds__(256) void combine_kernel(const bf16* __restrict__ part,
                                                      const bf16* __restrict__ apart,
                                                      const float* __restrict__ b2,
                                                      const float* __restrict__ mix,
                                                      float* __restrict__ out) {
    int i = blockIdx.x * 256 + threadIdx.x;
    int base = i * 4;
    int row = base / DIM;
    int c = base - row * DIM;
    float mx = mix[row & (SEQ - 1)];
    bf16x4 p0 = *(const bf16x4*)(part + base);
    bf16x4 p1 = *(const bf16x4*)(part + (size_t)1 * ROWS * DIM + base);
    bf16x4 p2 = *(const bf16x4*)(part + (size_t)2 * ROWS * DIM + base);
    bf16x4 p3 = *(const bf16x4*)(part + (size_t)3 * ROWS * DIM + base);
    bf16x4 a0 = *(const bf16x4*)(apart + base);
    bf16x4 a1 = *(const bf16x4*)(apart + (size_t)1 * ROWS * DIM + base);
    float4 o;
    float* po = &o.x;
#pragma unroll
    for (int k = 0; k < 4; k++) {
        float main_v = (float)p0[k] + (float)p1[k] + (float)p2[k] + (float)p3[k] + b2[c + k];
        float ap_v = (float)a0[k] + (float)a1[k];
        po[k] = (1.0f - mx) * main_v + mx * ap_v;
    }
    *(float4*)(out + base) = o;
}

// ---------------- launch ----------------
extern "C" void kernel_launch(void* const* d_in, const int* in_sizes, int n_in,
                              void* d_out, int out_size, void* d_ws, size_t ws_size,
                              hipStream_t stream) {
    const float* x    = (const float*)d_in[0];
    const int* levels = (const int*)d_in[1];
    const float* gamma= (const float*)d_in[2];
    const float* beta = (const float*)d_in[3];
    const float* W1   = (const float*)d_in[4];
    const float* b1   = (const float*)d_in[5];
    const float* W2   = (const float*)d_in[6];
    const float* b2   = (const float*)d_in[7];
    const float* A1   = (const float*)d_in[8];
    const float* a1b  = (const float*)d_in[9];
    const float* A2   = (const float*)d_in[10];
    const float* a2b  = (const float*)d_in[11];
    const float* lmw  = (const float*)d_in[12];
    float* out = (float*)d_out;

    char* p = (char*)d_ws;
    auto alloc = [&](size_t bytes) {
        char* r = p;
        p += (bytes + 255) & ~(size_t)255;
        return r;
    };
    bf16* Xn   = (bf16*)alloc((size_t)ROWS * DIM * 2);
    bf16* W1t  = (bf16*)alloc((size_t)HID * DIM * 2);
    bf16* W2t  = (bf16*)alloc((size_t)DIM * HID * 2);
    bf16* A1t  = (bf16*)alloc((size_t)NLEV * HID2 * DIM * 2);
    bf16* A2t  = (bf16*)alloc((size_t)NLEV * DIM * HID2 * 2);
    bf16* H    = (bf16*)alloc((size_t)ROWS * HID * 2);
    bf16* HL   = (bf16*)alloc((size_t)MAXPAD * HID2 * 2);
    bf16* part = (bf16*)alloc((size_t)4 * ROWS * DIM * 2);
    bf16* apart= (bf16*)alloc((size_t)2 * ROWS * DIM * 2);
    float* mix = (float*)alloc(SEQ * 4);
    int* row_index = (int*)alloc(MAXPAD * 4);
    int* tile_meta = (int*)alloc(MAXTILES * 4);
    float* zbuf    = (float*)alloc(2048);   // 2 KB zero page (>=768 bf16 + chunk)

    prep_kernel<<<dim3(1 + ROWS + 576 + 576 + 2592 + 2592), dim3(256), 0, stream>>>(
        x, levels, gamma, beta, W1, W2, A1, A2, lmw,
        Xn, W1t, W2t, A1t, A2t, mix, row_index, tile_meta, zbuf);

    // mlp1: gemm1 (768) + agemm1 (492)
    mlp1_kernel<<<dim3(768 + MAXTILES * 12), dim3(256), 0, stream>>>(
        Xn, W1t, b1, H, A1t, a1b, row_index, tile_meta, (const bf16*)zbuf, HL);

    // mlp2: gemm2 splitK4 (768) + agemm2 splitK2 (492)
    mlp2_kernel<<<dim3(768 + MAXTILES * 12), dim3(256), 0, stream>>>(
        H, W2t, part, HL, A2t, a2b, row_index, tile_meta, apart);

    combine_kernel<<<dim3(ROWS * DIM / 1024), dim3(256), 0, stream>>>(
        part, apart, b2, mix, out);
}

// Round 7
// 279.569 us; speedup vs baseline: 1.4634x; 1.4634x over previous
//
#include <hip/hip_runtime.h>
#include <hip/hip_bf16.h>
#include <math.h>

typedef __bf16 bf16;
typedef __bf16 bf16x4 __attribute__((ext_vector_type(4)));
typedef __bf16 bf16x8 __attribute__((ext_vector_type(8)));
typedef float f32x4 __attribute__((ext_vector_type(4)));

#define DIM 768
#define HID 3072
#define HID2 1536
#define NLEV 9
#define SEQ 2048
#define ROWS 4096            // BATCH*SEQ
#define MAXPAD 5248          // ROWS + NLEV*128 (rounded)
#define MAXTILES 41          // MAXPAD/128

// ---------------- async global->LDS 16B ----------------
__device__ __forceinline__ void gld16(const void* g, void* l) {
    __builtin_amdgcn_global_load_lds(
        (const __attribute__((address_space(1))) void*)g,
        (__attribute__((address_space(3))) void*)l, 16, 0, 0);
}

// fast tanh-GELU: max |err| vs exact-erf gelu ~5e-4
__device__ __forceinline__ float fast_gelu(float v) {
    float v2 = v * v;
    float twou = v * (1.59576912f + 0.071354816f * v2);
    float t = __expf(twou);
    return v * t / (t + 1.0f);
}

// ================= PREP bodies =================

__device__ __forceinline__ void ln_body(int row, float* sm,
                                        const float* __restrict__ x,
                                        const float* __restrict__ gamma,
                                        const float* __restrict__ beta,
                                        bf16* __restrict__ xn) {
    int tid = threadIdx.x;
    const float* xr = x + (size_t)row * DIM;
    float v0 = xr[tid], v1 = xr[tid + 256], v2 = xr[tid + 512];
    float s = v0 + v1 + v2;
    float q = v0 * v0 + v1 * v1 + v2 * v2;
    for (int off = 32; off; off >>= 1) {
        s += __shfl_down(s, off, 64);
        q += __shfl_down(q, off, 64);
    }
    int wv = tid >> 6, ln = tid & 63;
    if (ln == 0) { sm[wv] = s; sm[4 + wv] = q; }
    __syncthreads();
    if (tid == 0) {
        float S = sm[0] + sm[1] + sm[2] + sm[3];
        float Q = sm[4] + sm[5] + sm[6] + sm[7];
        float m = S * (1.0f / DIM);
        float var = Q * (1.0f / DIM) - m * m;
        sm[8] = m;
        sm[9] = rsqrtf(var + 1e-5f);
    }
    __syncthreads();
    float m = sm[8], r = sm[9];
    bf16* xo = xn + (size_t)row * DIM;
    xo[tid]       = (bf16)((v0 - m) * r * gamma[tid]       + beta[tid]);
    xo[tid + 256] = (bf16)((v1 - m) * r * gamma[tid + 256] + beta[tid + 256]);
    xo[tid + 512] = (bf16)((v2 - m) * r * gamma[tid + 512] + beta[tid + 512]);
}

// 64x64 tile transpose: fp32 [R][C] -> bf16 [C][R]. sm = 64*65 floats (16.6 KB).
__device__ __forceinline__ void transpose_body64(float* sm,
                                                 const float* __restrict__ inb,
                                                 bf16* __restrict__ outb,
                                                 int R, int C, int bx, int by) {
    int tid = threadIdx.x;
    int ty = tid >> 4;
    int tx4 = (tid & 15) * 4;
#pragma unroll
    for (int p = 0; p < 4; p++) {
        int rloc = p * 16 + ty;
        int row = by * 64 + rloc;
        float4 v = *(const float4*)(inb + (size_t)row * C + bx * 64 + tx4);
        sm[rloc * 65 + tx4 + 0] = v.x;
        sm[rloc * 65 + tx4 + 1] = v.y;
        sm[rloc * 65 + tx4 + 2] = v.z;
        sm[rloc * 65 + tx4 + 3] = v.w;
    }
    __syncthreads();
    int ch = tid & 7;
    int ocb = tid >> 3;
#pragma unroll
    for (int p = 0; p < 2; p++) {
        int oc = p * 32 + ocb;
        bf16x8 tmp;
#pragma unroll
        for (int k = 0; k < 8; k++) tmp[k] = (bf16)sm[(ch * 8 + k) * 65 + oc];
        *(bf16x8*)(outb + (size_t)(bx * 64 + oc) * R + by * 64 + ch * 8) = tmp;
    }
}

__device__ __forceinline__ void routing_body(float* sm,
                                             const int* __restrict__ levels_info,
                                             const float* __restrict__ lmw,
                                             float* __restrict__ mix,
                                             int* __restrict__ row_index,
                                             int* __restrict__ tile_meta,
                                             float* __restrict__ zbuf) {
    int* cnt = (int*)sm;
    int* cur = cnt + NLEV;
    int* off = cur + NLEV;
    float* mixv = (float*)(off + NLEV);
    int tid = threadIdx.x;
    if (tid < NLEV) { cnt[tid] = 0; cur[tid] = 0; }
    __syncthreads();
    for (int s = tid; s < SEQ; s += 256) {
        int d = levels_info[s * 4];
        d = d < 0 ? 0 : (d > 8 ? 8 : d);
        atomicAdd(&cnt[d], 1);
    }
    for (int i = tid; i < MAXPAD; i += 256) row_index[i] = -1;
    for (int i = tid; i < 512; i += 256) zbuf[i] = 0.0f;   // 2 KB zero page
    __syncthreads();
    if (tid == 0) {
        float mx = lmw[0];
        for (int l = 1; l < NLEV; l++) mx = fmaxf(mx, lmw[l]);
        float denom = 0.f;
        for (int l = 0; l < NLEV; l++) denom += (float)cnt[l] * expf(lmw[l] - mx);
        float inv = 1.0f / denom;
        int running = 0, t = 0;
        for (int l = 0; l < NLEV; l++) {
            mixv[l] = expf(lmw[l] - mx) * inv;
            off[l] = running;
            int seg = (2 * cnt[l] + 127) & ~127;
            for (int k = 0; k < seg / 128; k++) tile_meta[t++] = l;
            running += seg;
        }
        for (; t < MAXTILES; t++) tile_meta[t] = -1;
    }
    __syncthreads();
    for (int s = tid; s < SEQ; s += 256) {
        int d = levels_info[s * 4];
        d = d < 0 ? 0 : (d > 8 ? 8 : d);
        int p = atomicAdd(&cur[d], 2);
        row_index[off[d] + p]     = s;
        row_index[off[d] + p + 1] = s + SEQ;
        mix[s] = mixv[d];
    }
}

// ---------------- prep: routing + LN + W1t + A1t only ----------------
__global__ __launch_bounds__(256) void prep_kernel(const float* __restrict__ x,
                                                   const int* __restrict__ levels_info,
                                                   const float* __restrict__ gamma,
                                                   const float* __restrict__ beta,
                                                   const float* __restrict__ W1,
                                                   const float* __restrict__ A1,
                                                   const float* __restrict__ lmw,
                                                   bf16* __restrict__ Xn,
                                                   bf16* __restrict__ W1t,
                                                   bf16* __restrict__ A1t,
                                                   float* __restrict__ mix,
                                                   int* __restrict__ row_index,
                                                   int* __restrict__ tile_meta,
                                                   float* __restrict__ zbuf) {
    __shared__ __align__(16) float sm[64 * 65];
    int bid = blockIdx.x;
    if (bid == 0) { routing_body(sm, levels_info, lmw, mix, row_index, tile_meta, zbuf); return; }
    bid -= 1;
    if (bid < ROWS) { ln_body(bid, sm, x, gamma, beta, Xn); return; }
    bid -= ROWS;
    if (bid < 576) {  // W1 [768,3072] -> [3072,768]: 48 bx x 12 by
        transpose_body64(sm, W1, W1t, DIM, HID, bid % 48, bid / 48);
        return;
    }
    bid -= 576;
    {   // A1[lvl] [768,1536] -> [1536,768]: 24 bx x 12 by, 288/level
        int bz = bid / 288, r = bid % 288;
        transpose_body64(sm, A1 + (size_t)bz * DIM * HID2, A1t + (size_t)bz * DIM * HID2,
                         DIM, HID2, r % 24, r / 24);
    }
}

// ---------------- double-buffered GEMM K-loop, XOR-swizzled LDS, full unroll ----------------
// smem layout: As = smem[0..8191] (2 x 4096-elem buffers), Bs = smem[8192..16383].
template<int KT>
__device__ __forceinline__ void gemm_loop_db(const bf16* ga0, const bf16* ga1,
                                             const bf16* gb0, const bf16* gb1,
                                             bf16* As, bf16* Bs,
                                             f32x4 (&acc)[4][4]) {
    int tid = threadIdx.x;
    int wv = tid >> 6;
    int lane = tid & 63;
    int wm = wv >> 1, wn = wv & 1;
    int swz = (lane >> 1) & 3;
    int achunk = ((lane >> 4) ^ swz) * 8;
    int aoff = ((wm * 64) + (lane & 15)) * 32 + achunk;
    int boff = ((wn * 64) + (lane & 15)) * 32 + achunk;
    gld16(ga0, As + wv * 512);
    gld16(ga1, As + 2048 + wv * 512);
    gld16(gb0, Bs + wv * 512);
    gld16(gb1, Bs + 2048 + wv * 512);
    ga0 += 32; ga1 += 32; gb0 += 32; gb1 += 32;
#pragma unroll
    for (int kt = 0; kt < KT; ++kt) {
        __syncthreads();
        const int cur = (kt & 1) << 12;
        const int nxt = cur ^ 4096;
        if (kt + 1 < KT) {
            gld16(ga0, As + nxt + wv * 512);
            gld16(ga1, As + nxt + 2048 + wv * 512);
            gld16(gb0, Bs + nxt + wv * 512);
            gld16(gb1, Bs + nxt + 2048 + wv * 512);
            ga0 += 32; ga1 += 32; gb0 += 32; gb1 += 32;
        }
        bf16x8 af[4], bfr[4];
#pragma unroll
        for (int i = 0; i < 4; i++) af[i] = *(const bf16x8*)(As + cur + aoff + i * 512);
#pragma unroll
        for (int j = 0; j < 4; j++) bfr[j] = *(const bf16x8*)(Bs + cur + boff + j * 512);
#pragma unroll
        for (int i = 0; i < 4; i++)
#pragma unroll
            for (int j = 0; j < 4; j++)
                acc[i][j] = __builtin_amdgcn_mfma_f32_16x16x32_bf16(af[i], bfr[j], acc[i][j], 0, 0, 0);
    }
}

#define ACC_INIT(acc) \
    _Pragma("unroll") for (int i = 0; i < 4; i++) \
    _Pragma("unroll") for (int j = 0; j < 4; j++) acc[i][j] = (f32x4){0.f, 0.f, 0.f, 0.f};

// producer-side swizzled chunk index for global fetch
#define SWZ_CG(tid) (((tid) & 3) ^ (((tid) >> 3) & 3))

// contiguous 128B-row store of a wave's 64x64 bf16 tile staged in cbuf
__device__ __forceinline__ void store_tile(const bf16* cbuf, int lane,
                                           bf16* gptr, int ldg) {
#pragma unroll
    for (int p = 0; p < 8; p++) {
        int lrow = p * 8 + (lane >> 3);
        int chunk = (lane & 7) * 8;
        bf16x8 v = *(const bf16x8*)(cbuf + lrow * 64 + chunk);
        *(bf16x8*)(gptr + (size_t)lrow * ldg + chunk) = v;
    }
}

// ---------------- mlp1: gemm1 + agemm1 + backfilled W2/A2 transposes ----------------
__global__ __launch_bounds__(256) void mlp1_kernel(const bf16* __restrict__ Xn,
                                                   const bf16* __restrict__ W1t,
                                                   const float* __restrict__ b1,
                                                   bf16* __restrict__ H,
                                                   const bf16* __restrict__ A1t,
                                                   const float* __restrict__ a1b,
                                                   const int* __restrict__ row_index,
                                                   const int* __restrict__ tile_meta,
                                                   const bf16* __restrict__ zbuf,
                                                   bf16* __restrict__ HL,
                                                   const float* __restrict__ W2,
                                                   const float* __restrict__ A2,
                                                   bf16* __restrict__ W2t,
                                                   bf16* __restrict__ A2t) {
    __shared__ __align__(16) bf16 smem[16384];
    bf16* As = smem;
    bf16* Bs = smem + 8192;
    int bid = blockIdx.x, tid = threadIdx.x;
    int r0 = tid >> 2, cg = SWZ_CG(tid);
    int lane = tid & 63, wv = tid >> 6, wm = wv >> 1, wn = wv & 1;
    bf16* cbuf = smem + wv * 4096;

    if (bid < 768) {
        // ---- gemm1: nb slow (24), mb fast (32), KT=24 ----
        int nb = bid / 32, mb = bid % 32;
        f32x4 acc[4][4];
        ACC_INIT(acc);
        const bf16* ga0 = Xn + (size_t)(mb * 128 + r0) * DIM + cg * 8;
        const bf16* ga1 = ga0 + (size_t)64 * DIM;
        const bf16* gb0 = W1t + (size_t)(nb * 128 + r0) * DIM + cg * 8;
        const bf16* gb1 = gb0 + (size_t)64 * DIM;
        gemm_loop_db<24>(ga0, ga1, gb0, gb1, As, Bs, acc);
        int cbase = nb * 128 + wn * 64 + (lane & 15);
        __syncthreads();
#pragma unroll
        for (int j = 0; j < 4; j++) {
            float bias = b1[cbase + j * 16];
#pragma unroll
            for (int i = 0; i < 4; i++)
#pragma unroll
                for (int r = 0; r < 4; r++) {
                    int lrow = i * 16 + ((lane >> 4) << 2) + r;
                    int lcol = j * 16 + (lane & 15);
                    cbuf[lrow * 64 + lcol] = (bf16)fast_gelu(acc[i][j][r] + bias);
                }
        }
        __syncthreads();
        store_tile(cbuf, lane, H + (size_t)(mb * 128 + wm * 64) * HID + nb * 128 + wn * 64, HID);
    } else if (bid < 1260) {
        // ---- agemm1: 41 tiles x 12 N, KT=24 ----
        int t2 = bid - 768;
        int nb = t2 % 12, t = t2 / 12;
        int lvl = tile_meta[t];
        if (lvl < 0) return;
        f32x4 acc[4][4];
        ACC_INIT(acc);
        int ridx0 = row_index[t * 128 + r0];
        int ridx1 = row_index[t * 128 + 64 + r0];
        const bf16* ga0 = (ridx0 >= 0) ? (Xn + (size_t)ridx0 * DIM + cg * 8) : (zbuf + cg * 8);
        const bf16* ga1 = (ridx1 >= 0) ? (Xn + (size_t)ridx1 * DIM + cg * 8) : (zbuf + cg * 8);
        const bf16* Bl = A1t + (size_t)lvl * HID2 * DIM;
        const bf16* gb0 = Bl + (size_t)(nb * 128 + r0) * DIM + cg * 8;
        const bf16* gb1 = gb0 + (size_t)64 * DIM;
        gemm_loop_db<24>(ga0, ga1, gb0, gb1, As, Bs, acc);
        int cbase = nb * 128 + wn * 64 + (lane & 15);
        __syncthreads();
#pragma unroll
        for (int j = 0; j < 4; j++) {
            float bias = a1b[lvl * HID2 + cbase + j * 16];
#pragma unroll
            for (int i = 0; i < 4; i++)
#pragma unroll
                for (int r = 0; r < 4; r++) {
                    int lrow = i * 16 + ((lane >> 4) << 2) + r;
                    int lcol = j * 16 + (lane & 15);
                    cbuf[lrow * 64 + lcol] = (bf16)fmaxf(acc[i][j][r] + bias, 0.0f);
                }
        }
        __syncthreads();
        store_tile(cbuf, lane, HL + (size_t)(t * 128 + wm * 64) * HID2 + nb * 128 + wn * 64, HID2);
    } else if (bid < 1836) {
        // ---- W2 transpose backfill: [3072,768] -> [768,3072] ----
        int idx = bid - 1260;
        transpose_body64((float*)smem, W2, W2t, HID, DIM, idx % 12, idx / 12);
    } else {
        // ---- A2 transpose backfill: [1536,768] -> [768,1536] per level ----
        int idx = bid - 1836;
        int bz = idx / 288, r = idx % 288;
        transpose_body64((float*)smem, A2 + (size_t)bz * HID2 * DIM,
                         A2t + (size_t)bz * HID2 * DIM, HID2, DIM, r % 12, r / 12);
    }
}

// ---------------- mlp2: gemm2 splitK2 (KT=48) + agemm2 (KT=48) ----------------
__global__ __launch_bounds__(256) void mlp2_kernel(const bf16* __restrict__ H,
                                                   const bf16* __restrict__ W2t,
                                                   bf16* __restrict__ part,   // [2][ROWS*DIM]
                                                   const bf16* __restrict__ HL,
                                                   const bf16* __restrict__ A2t,
                                                   const float* __restrict__ a2b,
                                                   const int* __restrict__ row_index,
                                                   const int* __restrict__ tile_meta,
                                                   bf16* __restrict__ apart) { // [ROWS*DIM]
    __shared__ __align__(16) bf16 smem[16384];
    bf16* As = smem;
    bf16* Bs = smem + 8192;
    int bid = blockIdx.x, tid = threadIdx.x;
    int r0 = tid >> 2, cg = SWZ_CG(tid);
    int lane = tid & 63, wv = tid >> 6, wm = wv >> 1, wn = wv & 1;
    bf16* cbuf = smem + wv * 4096;
    f32x4 acc[4][4];
    ACC_INIT(acc);

    if (bid < 384) {
        // ---- gemm2: mb slow? no: mb = bid/12 (H chunk shared by resident window), (nb,ks) fast ----
        int cc = bid % 12;
        int nb = cc >> 1, ks = cc & 1;
        int mb = bid / 12;
        const bf16* ga0 = H + (size_t)(mb * 128 + r0) * HID + ks * 1536 + cg * 8;
        const bf16* ga1 = ga0 + (size_t)64 * HID;
        const bf16* gb0 = W2t + (size_t)(nb * 128 + r0) * HID + ks * 1536 + cg * 8;
        const bf16* gb1 = gb0 + (size_t)64 * HID;
        gemm_loop_db<48>(ga0, ga1, gb0, gb1, As, Bs, acc);
        __syncthreads();
#pragma unroll
        for (int j = 0; j < 4; j++)
#pragma unroll
            for (int i = 0; i < 4; i++)
#pragma unroll
                for (int r = 0; r < 4; r++) {
                    int lrow = i * 16 + ((lane >> 4) << 2) + r;
                    int lcol = j * 16 + (lane & 15);
                    cbuf[lrow * 64 + lcol] = (bf16)acc[i][j][r];
                }
        __syncthreads();
        bf16* pk = part + (size_t)ks * ROWS * DIM;
        store_tile(cbuf, lane, pk + (size_t)(mb * 128 + wm * 64) * DIM + nb * 128 + wn * 64, DIM);
    } else {
        // ---- agemm2: 41 tiles x 6 N, full K=1536 ----
        int t2 = bid - 384;
        int nb = t2 % 6, t = t2 / 6;
        int lvl = tile_meta[t];
        if (lvl < 0) return;
        const bf16* ga0 = HL + (size_t)(t * 128 + r0) * HID2 + cg * 8;
        const bf16* ga1 = ga0 + (size_t)64 * HID2;
        const bf16* Bl = A2t + (size_t)lvl * DIM * HID2;
        const bf16* gb0 = Bl + (size_t)(nb * 128 + r0) * HID2 + cg * 8;
        const bf16* gb1 = gb0 + (size_t)64 * HID2;
        gemm_loop_db<48>(ga0, ga1, gb0, gb1, As, Bs, acc);
        int cbase = nb * 128 + wn * 64 + (lane & 15);
        __syncthreads();
#pragma unroll
        for (int j = 0; j < 4; j++) {
            float bias = a2b[lvl * DIM + cbase + j * 16];
#pragma unroll
            for (int i = 0; i < 4; i++)
#pragma unroll
                for (int r = 0; r < 4; r++) {
                    int lrow = i * 16 + ((lane >> 4) << 2) + r;
                    int lcol = j * 16 + (lane & 15);
                    cbuf[lrow * 64 + lcol] = (bf16)(acc[i][j][r] + bias);
                }
        }
        __syncthreads();
        // gathered row store, still 128B-contiguous per row
        int colg = nb * 128 + wn * 64;
#pragma unroll
        for (int p = 0; p < 8; p++) {
            int lrow = p * 8 + (lane >> 3);
            int chunk = (lane & 7) * 8;
            int rg = row_index[t * 128 + wm * 64 + lrow];
            if (rg >= 0) {
                bf16x8 v = *(const bf16x8*)(cbuf + lrow * 64 + chunk);
                *(bf16x8*)(apart + (size_t)rg * DIM + colg + chunk) = v;
            }
        }
    }
}

// ---------------- combine: out = (1-mix)*(p0+p1+b2) + mix*apart ----------------
__global__ __launch_bounds__(256) void combine_kernel(const bf16* __restrict__ part,
                                                      const bf16* __restrict__ apart,
                                                      const float* __restrict__ b2,
                                                      const float* __restrict__ mix,
                                                      float* __restrict__ out) {
    int i = blockIdx.x * 256 + threadIdx.x;
    int base = i * 4;
    int row = base / DIM;
    int c = base - row * DIM;
    float mx = mix[row & (SEQ - 1)];
    bf16x4 p0 = *(const bf16x4*)(part + base);
    bf16x4 p1 = *(const bf16x4*)(part + (size_t)ROWS * DIM + base);
    bf16x4 a0 = *(const bf16x4*)(apart + base);
    float4 o;
    float* po = &o.x;
#pragma unroll
    for (int k = 0; k < 4; k++) {
        float main_v = (float)p0[k] + (float)p1[k] + b2[c + k];
        po[k] = (1.0f - mx) * main_v + mx * (float)a0[k];
    }
    *(float4*)(out + base) = o;
}

// ---------------- launch ----------------
extern "C" void kernel_launch(void* const* d_in, const int* in_sizes, int n_in,
                              void* d_out, int out_size, void* d_ws, size_t ws_size,
                              hipStream_t stream) {
    const float* x    = (const float*)d_in[0];
    const int* levels = (const int*)d_in[1];
    const float* gamma= (const float*)d_in[2];
    const float* beta = (const float*)d_in[3];
    const float* W1   = (const float*)d_in[4];
    const float* b1   = (const float*)d_in[5];
    const float* W2   = (const float*)d_in[6];
    const float* b2   = (const float*)d_in[7];
    const float* A1   = (const float*)d_in[8];
    const float* a1b  = (const float*)d_in[9];
    const float* A2   = (const float*)d_in[10];
    const float* a2b  = (const float*)d_in[11];
    const float* lmw  = (const float*)d_in[12];
    float* out = (float*)d_out;

    char* p = (char*)d_ws;
    auto alloc = [&](size_t bytes) {
        char* r = p;
        p += (bytes + 255) & ~(size_t)255;
        return r;
    };
    bf16* Xn   = (bf16*)alloc((size_t)ROWS * DIM * 2);
    bf16* W1t  = (bf16*)alloc((size_t)HID * DIM * 2);
    bf16* W2t  = (bf16*)alloc((size_t)DIM * HID * 2);
    bf16* A1t  = (bf16*)alloc((size_t)NLEV * HID2 * DIM * 2);
    bf16* A2t  = (bf16*)alloc((size_t)NLEV * DIM * HID2 * 2);
    bf16* H    = (bf16*)alloc((size_t)ROWS * HID * 2);
    bf16* HL   = (bf16*)alloc((size_t)MAXPAD * HID2 * 2);
    bf16* part = (bf16*)alloc((size_t)2 * ROWS * DIM * 2);
    bf16* apart= (bf16*)alloc((size_t)ROWS * DIM * 2);
    float* mix = (float*)alloc(SEQ * 4);
    int* row_index = (int*)alloc(MAXPAD * 4);
    int* tile_meta = (int*)alloc(MAXTILES * 4);
    float* zbuf    = (float*)alloc(2048);   // 2 KB zero page

    // prep: routing(1) + LN(4096) + W1t(576) + A1t(2592)
    prep_kernel<<<dim3(1 + ROWS + 576 + 2592), dim3(256), 0, stream>>>(
        x, levels, gamma, beta, W1, A1, lmw,
        Xn, W1t, A1t, mix, row_index, tile_meta, zbuf);

    // mlp1: gemm1(768) + agemm1(492) + W2t(576) + A2t(2592) backfill
    mlp1_kernel<<<dim3(768 + 492 + 576 + 2592), dim3(256), 0, stream>>>(
        Xn, W1t, b1, H, A1t, a1b, row_index, tile_meta, (const bf16*)zbuf, HL,
        W2, A2, W2t, A2t);

    // mlp2: gemm2 splitK2 (384, KT=48) + agemm2 (246, KT=48)
    mlp2_kernel<<<dim3(384 + MAXTILES * 6), dim3(256), 0, stream>>>(
        H, W2t, part, HL, A2t, a2b, row_index, tile_meta, apart);

    combine_kernel<<<dim3(ROWS * DIM / 1024), dim3(256), 0, stream>>>(
        part, apart, b2, mix, out);
}